// Round 5
// baseline (195.189 us; speedup 1.0000x reference)
//
#include <hip/hip_runtime.h>

#define LL   2048
#define BB   4
#define DD   512
#define HH   8
#define DKK  64
#define WBAND 12
#define NBAND 25   // 2*WBAND+1

typedef __attribute__((ext_vector_type(8))) short  bf16x8;
typedef __attribute__((ext_vector_type(4))) float  f32x4;

static __device__ __forceinline__ float bf2f(unsigned short u) {
    union { unsigned int i; float f; } c; c.i = ((unsigned int)u) << 16; return c.f;
}
static __device__ __forceinline__ unsigned short f2bf(float f) {
    union { float f; unsigned int i; } c; c.f = f;
    unsigned int x = c.i;
    return (unsigned short)((x + 0x7fffu + ((x >> 16) & 1u)) >> 16);  // RNE
}
static __device__ __forceinline__ bf16x8 pack8(float4 x0, float4 x1) {
    bf16x8 r;
    r[0] = (short)f2bf(x0.x); r[1] = (short)f2bf(x0.y);
    r[2] = (short)f2bf(x0.z); r[3] = (short)f2bf(x0.w);
    r[4] = (short)f2bf(x1.x); r[5] = (short)f2bf(x1.y);
    r[6] = (short)f2bf(x1.z); r[7] = (short)f2bf(x1.w);
    return r;
}

// ---------------------------------------------------------------------------
// cvt: fp32 -> bf16 for q, k (L*B*D each) and Wq, Wk (D*D each).
// One 8-float chunk per thread. Chunk partition:
//   [0, 524288)          -> q
//   [524288, 1048576)    -> k
//   [1048576, 1081344)   -> Wq
//   [1081344, 1114112)   -> Wk
// ---------------------------------------------------------------------------
#define CHUNKS_QK  524288    // (L*B*D)/8
#define CHUNKS_W   32768     // (D*D)/8
#define CHUNKS_TOT (2*CHUNKS_QK + 2*CHUNKS_W)

__global__ __launch_bounds__(256) void cvt_kernel(
    const float* __restrict__ q, const float* __restrict__ k,
    const float* __restrict__ Wq, const float* __restrict__ Wk,
    unsigned short* __restrict__ qb, unsigned short* __restrict__ kb,
    unsigned short* __restrict__ wqb, unsigned short* __restrict__ wkb)
{
    const int cid = blockIdx.x * 256 + threadIdx.x;
    const float* src;
    unsigned short* dst;
    int loc;
    if (cid < CHUNKS_QK)                { src = q;  dst = qb;  loc = cid; }
    else if (cid < 2 * CHUNKS_QK)       { src = k;  dst = kb;  loc = cid - CHUNKS_QK; }
    else if (cid < 2 * CHUNKS_QK + CHUNKS_W) { src = Wq; dst = wqb; loc = cid - 2 * CHUNKS_QK; }
    else                                { src = Wk; dst = wkb; loc = cid - 2 * CHUNKS_QK - CHUNKS_W; }
    const float4* p = (const float4*)src + (size_t)loc * 2;
    *(bf16x8*)(dst + (size_t)loc * 8) = pack8(p[0], p[1]);
}

// ---------------------------------------------------------------------------
// proj: Out[b,h,l,dk] = ((X @ Wm^T)[m,n] + bias[n]) * scale, all-bf16 inputs.
// Tile 64x64, 4 waves (wave w owns n-slice 16w..16w+15). grid (128, 8, 2);
// z selects {Q-proj, K-proj}. 2048 blocks -> 8 blocks/CU, full occupancy.
// ---------------------------------------------------------------------------
__global__ __launch_bounds__(256) void proj_mfma(
    const unsigned short* __restrict__ Xq, const unsigned short* __restrict__ Xk,
    const unsigned short* __restrict__ Wqb, const unsigned short* __restrict__ Wkb,
    const float* __restrict__ bq, const float* __restrict__ bk,
    unsigned short* __restrict__ Qh, unsigned short* __restrict__ Kh)
{
    const int which = blockIdx.z;
    const unsigned short* X  = which ? Xk  : Xq;
    const unsigned short* Wm = which ? Wkb : Wqb;
    const float* bias        = which ? bk  : bq;
    unsigned short* Out      = which ? Kh  : Qh;
    const float scale        = which ? 1.0f : 0.125f;

    const int t  = threadIdx.x;
    const int w  = t >> 6;
    const int l  = t & 63;
    const int mb = blockIdx.x * 64;
    const int nb = blockIdx.y * 64;
    const int lr = l & 15;
    const int lk = (l >> 4) * 8;

    f32x4 acc[4] = {};

#pragma unroll 4
    for (int ks = 0; ks < DD; ks += 32) {
        const bf16x8 b = *(const bf16x8*)&Wm[(size_t)(nb + 16 * w + lr) * DD + ks + lk];
        bf16x8 a[4];
#pragma unroll
        for (int mi = 0; mi < 4; ++mi)
            a[mi] = *(const bf16x8*)&X[(size_t)(mb + 16 * mi + lr) * DD + ks + lk];
#pragma unroll
        for (int mi = 0; mi < 4; ++mi)
            acc[mi] = __builtin_amdgcn_mfma_f32_16x16x32_bf16(a[mi], b, acc[mi], 0, 0, 0);
    }

    const int n  = nb + 16 * w + lr;
    const int h  = n >> 6;
    const int dk = n & 63;
    const float bs = bias[n];
#pragma unroll
    for (int mi = 0; mi < 4; ++mi)
#pragma unroll
        for (int j = 0; j < 4; ++j) {
            const int m    = mb + 16 * mi + (l >> 4) * 4 + j;
            const int lseq = m >> 2;
            const int bidx = m & 3;
            Out[(((size_t)(bidx * HH + h)) * LL + lseq) * DKK + dk] =
                f2bf((acc[mi][j] + bs) * scale);
        }
}

// ---------------------------------------------------------------------------
// scorez: Z[bh,q] = sum_k exp( Qh[bh,q] . Kh[bh,k] )   (Q pre-scaled by 1/8)
// ---------------------------------------------------------------------------
__global__ __launch_bounds__(256) void scorez_mfma(
    const unsigned short* __restrict__ Qh, const unsigned short* __restrict__ Kh,
    float* __restrict__ Z)
{
    __shared__ float Zp[4][64];
    const int t  = threadIdx.x;
    const int w  = t >> 6;
    const int l  = t & 63;
    const int bh = blockIdx.y;
    const int qb = blockIdx.x * 64;
    const int lr = l & 15;
    const int lk = (l >> 4) * 8;
    const unsigned short* Qp = Qh + (size_t)bh * LL * DKK;
    const unsigned short* Kp = Kh + (size_t)bh * LL * DKK;

    bf16x8 qa[4][2];
#pragma unroll
    for (int r = 0; r < 4; ++r)
#pragma unroll
        for (int s = 0; s < 2; ++s)
            qa[r][s] = *(const bf16x8*)&Qp[(size_t)(qb + 16 * r + lr) * DKK + 32 * s + lk];

    float zacc[4][4] = {};
    const int k0 = w * 512;
    for (int kt = k0; kt < k0 + 512; kt += 16) {
        const bf16x8 kb0 = *(const bf16x8*)&Kp[(size_t)(kt + lr) * DKK + lk];
        const bf16x8 kb1 = *(const bf16x8*)&Kp[(size_t)(kt + lr) * DKK + 32 + lk];
#pragma unroll
        for (int r = 0; r < 4; ++r) {
            f32x4 acc = {0.f, 0.f, 0.f, 0.f};
            acc = __builtin_amdgcn_mfma_f32_16x16x32_bf16(qa[r][0], kb0, acc, 0, 0, 0);
            acc = __builtin_amdgcn_mfma_f32_16x16x32_bf16(qa[r][1], kb1, acc, 0, 0, 0);
#pragma unroll
            for (int j = 0; j < 4; ++j)
                zacc[r][j] += __expf(acc[j]);
        }
    }

#pragma unroll
    for (int m = 8; m >= 1; m >>= 1)
#pragma unroll
        for (int r = 0; r < 4; ++r)
#pragma unroll
            for (int j = 0; j < 4; ++j)
                zacc[r][j] += __shfl_xor(zacc[r][j], m, 64);

    if (lr == 0) {
#pragma unroll
        for (int r = 0; r < 4; ++r)
#pragma unroll
            for (int j = 0; j < 4; ++j)
                Zp[w][16 * r + (l >> 4) * 4 + j] = zacc[r][j];
    }
    __syncthreads();
    if (t < 64)
        Z[(size_t)bh * LL + qb + t] = Zp[0][t] + Zp[1][t] + Zp[2][t] + Zp[3][t];
}

// ---------------------------------------------------------------------------
// weights: one WAVE per (b,q). Computes normalized band weights; writes them
// compact to wgtbuf AND scatters them into the pre-zeroed dense wout row.
// ---------------------------------------------------------------------------
__global__ __launch_bounds__(256) void weights_kernel(
    const unsigned short* __restrict__ Qh, const unsigned short* __restrict__ Kh,
    const float* __restrict__ Z, float* __restrict__ wgtbuf,
    float* __restrict__ wout)
{
    const int t = threadIdx.x;
    const int w = t >> 6;
    const int l = t & 63;
    const int idx = blockIdx.x * 4 + w;       // idx = b*L + q
    const int b = idx >> 11;
    const int q = idx & 2047;
    const int h = l >> 3;
    const int jslot = l & 7;

    bf16x8 qv[8];
    {
        const bf16x8* qp = (const bf16x8*)&Qh[(((size_t)b * HH + h) * LL + q) * DKK];
#pragma unroll
        for (int i = 0; i < 8; ++i) qv[i] = qp[i];
    }
    const float zinv = 1.0f / Z[((size_t)b * HH + h) * LL + q];

    float e[4];
#pragma unroll
    for (int c = 0; c < 4; ++c) {
        const int j = jslot + 8 * c;
        const int k = q - WBAND + j;
        float a = 0.f;
        if (j < NBAND && k >= 0 && k < LL) {
            const bf16x8* kp = (const bf16x8*)&Kh[(((size_t)b * HH + h) * LL + k) * DKK];
            float s = 0.f;
#pragma unroll
            for (int i = 0; i < 8; ++i) {
                const bf16x8 ka = kp[i];
#pragma unroll
                for (int ee = 0; ee < 8; ++ee)
                    s += bf2f((unsigned short)qv[i][ee]) * bf2f((unsigned short)ka[ee]);
            }
            a = __expf(s) * zinv;
        }
        e[c] = a;
    }

    // sum over heads (lane bits 3,4,5)
#pragma unroll
    for (int m = 8; m <= 32; m <<= 1)
#pragma unroll
        for (int c = 0; c < 4; ++c)
            e[c] += __shfl_xor(e[c], m, 64);

    // * dist, then band-sum over jslot (lane bits 0,1,2)
    float att[4];
    float part = 0.f;
#pragma unroll
    for (int c = 0; c < 4; ++c) {
        const int j = jslot + 8 * c;
        const float dd = (float)(j - WBAND);
        att[c] = (j < NBAND) ? e[c] * __expf(-0.5f * dd * dd) : 0.f;
        part += att[c];
    }
#pragma unroll
    for (int m = 1; m <= 4; m <<= 1)
        part += __shfl_xor(part, m, 64);
    const float winv = 1.0f / part;

    if (h == 0) {
        float* wrow = &wout[((size_t)b * LL + q) * LL];
#pragma unroll
        for (int c = 0; c < 4; ++c) {
            const int j = jslot + 8 * c;
            if (j < NBAND) {
                const float wv = att[c] * winv;
                wgtbuf[(size_t)idx * 32 + j] = wv;
                const int k = q - WBAND + j;
                if (k >= 0 && k < LL) wrow[k] = wv;
            }
        }
    }
}

// ---------------------------------------------------------------------------
// out: grid (L/8, B). Per block: 8 q rows. Register sliding window over v.
// ---------------------------------------------------------------------------
__global__ __launch_bounds__(256) void out_kernel(
    const float* __restrict__ wgtbuf, const float* __restrict__ v,
    float* __restrict__ out)
{
    __shared__ float lw[8][NBAND];
    const int t  = threadIdx.x;
    const int q0 = blockIdx.x * 8;
    const int b  = blockIdx.y;

    if (t < 8 * NBAND) {
        const int qq = t / NBAND;
        const int j  = t - qq * NBAND;
        lw[qq][j] = wgtbuf[((size_t)b * LL + q0 + qq) * 32 + j];
    }
    __syncthreads();

    const int qsub = t >> 7;
    const int d4   = t & 127;
    const int qs   = q0 + qsub * 4;
    const int kbase = qs - WBAND;
    f32x4 acc[4] = {{0,0,0,0},{0,0,0,0},{0,0,0,0},{0,0,0,0}};
#pragma unroll
    for (int kk = 0; kk < 28; ++kk) {
        const int k = kbase + kk;
        f32x4 vv = {0.f, 0.f, 0.f, 0.f};
        if (k >= 0 && k < LL)
            vv = *(const f32x4*)&v[((size_t)k * BB + b) * DD + d4 * 4];
#pragma unroll
        for (int qi = 0; qi < 4; ++qi) {
            const int j = kk - qi;
            if (j >= 0 && j < NBAND) {
                const float wv = lw[qsub * 4 + qi][j];
                acc[qi][0] += wv * vv[0]; acc[qi][1] += wv * vv[1];
                acc[qi][2] += wv * vv[2]; acc[qi][3] += wv * vv[3];
            }
        }
    }
#pragma unroll
    for (int qi = 0; qi < 4; ++qi) {
        const int q = qs + qi;
        __builtin_nontemporal_store(acc[qi],
            (f32x4*)&out[((size_t)q * BB + b) * DD + d4 * 4]);
    }
}

// ---------------------------------------------------------------------------
extern "C" void kernel_launch(void* const* d_in, const int* in_sizes, int n_in,
                              void* d_out, int out_size, void* d_ws, size_t ws_size,
                              hipStream_t stream) {
    const float* q  = (const float*)d_in[0];
    const float* k  = (const float*)d_in[1];
    const float* v  = (const float*)d_in[2];
    const float* Wq = (const float*)d_in[3];
    const float* bq = (const float*)d_in[4];
    const float* Wk = (const float*)d_in[5];
    const float* bk = (const float*)d_in[6];

    float* out  = (float*)d_out;                       // [L,B,D]
    float* wout = out + (size_t)LL * BB * DD;          // [B,L,L]

    unsigned short* Qh  = (unsigned short*)d_ws;                // bf16 [B,H,L,DK] 8 MB
    unsigned short* Kh  = Qh  + (size_t)BB * HH * LL * DKK;     // bf16 8 MB
    unsigned short* qbf = Kh  + (size_t)BB * HH * LL * DKK;     // bf16 [L*B][D] 8 MB
    unsigned short* kbf = qbf + (size_t)LL * BB * DD;           // bf16 8 MB
    unsigned short* wqb = kbf + (size_t)LL * BB * DD;           // bf16 [D][D] 0.5 MB
    unsigned short* wkb = wqb + (size_t)DD * DD;                // bf16 0.5 MB
    float* Z      = (float*)(wkb + (size_t)DD * DD);            // [B*H*L] 256 KB
    float* wgtbuf = Z + (size_t)BB * HH * LL;                   // [B*L][32] 1 MB

    // zero dense wout (band values scattered in by weights_kernel)
    hipMemsetAsync(wout, 0, (size_t)BB * LL * LL * sizeof(float), stream);

    cvt_kernel<<<CHUNKS_TOT / 256, 256, 0, stream>>>(q, k, Wq, Wk, qbf, kbf, wqb, wkb);

    proj_mfma<<<dim3(LL * BB / 64, DD / 64, 2), 256, 0, stream>>>(
        qbf, kbf, wqb, wkb, bq, bk, Qh, Kh);

    scorez_mfma<<<dim3(LL / 64, BB * HH), 256, 0, stream>>>(Qh, Kh, Z);

    weights_kernel<<<BB * LL / 4, 256, 0, stream>>>(Qh, Kh, Z, wgtbuf, wout);

    out_kernel<<<dim3(LL / 8, BB), 256, 0, stream>>>(wgtbuf, v, out);
}

// Round 7
// 130.201 us; speedup vs baseline: 1.4991x; 1.4991x over previous
//
#include <hip/hip_runtime.h>

#define LL   2048
#define BB   4
#define DD   512
#define HH   8
#define DKK  64
#define WBAND 12
#define NBAND 25   // 2*WBAND+1

typedef __attribute__((ext_vector_type(8))) short  bf16x8;
typedef __attribute__((ext_vector_type(4))) float  f32x4;

static __device__ __forceinline__ float bf2f(unsigned short u) {
    union { unsigned int i; float f; } c; c.i = ((unsigned int)u) << 16; return c.f;
}
static __device__ __forceinline__ unsigned short f2bf(float f) {
    union { float f; unsigned int i; } c; c.f = f;
    unsigned int x = c.i;
    return (unsigned short)((x + 0x7fffu + ((x >> 16) & 1u)) >> 16);  // RNE
}
static __device__ __forceinline__ bf16x8 pack8(float4 x0, float4 x1) {
    bf16x8 r;
    r[0] = (short)f2bf(x0.x); r[1] = (short)f2bf(x0.y);
    r[2] = (short)f2bf(x0.z); r[3] = (short)f2bf(x0.w);
    r[4] = (short)f2bf(x1.x); r[5] = (short)f2bf(x1.y);
    r[6] = (short)f2bf(x1.z); r[7] = (short)f2bf(x1.w);
    return r;
}

// ---------------------------------------------------------------------------
// cvt: fp32 -> bf16 for q, k (L*B*D each) and Wq, Wk (D*D each).
// ---------------------------------------------------------------------------
#define CHUNKS_QK  524288    // (L*B*D)/8
#define CHUNKS_W   32768     // (D*D)/8
#define CHUNKS_TOT (2*CHUNKS_QK + 2*CHUNKS_W)

__global__ __launch_bounds__(256) void cvt_kernel(
    const float* __restrict__ q, const float* __restrict__ k,
    const float* __restrict__ Wq, const float* __restrict__ Wk,
    unsigned short* __restrict__ qb, unsigned short* __restrict__ kb,
    unsigned short* __restrict__ wqb, unsigned short* __restrict__ wkb)
{
    const int cid = blockIdx.x * 256 + threadIdx.x;
    const float* src;
    unsigned short* dst;
    int loc;
    if (cid < CHUNKS_QK)                { src = q;  dst = qb;  loc = cid; }
    else if (cid < 2 * CHUNKS_QK)       { src = k;  dst = kb;  loc = cid - CHUNKS_QK; }
    else if (cid < 2 * CHUNKS_QK + CHUNKS_W) { src = Wq; dst = wqb; loc = cid - 2 * CHUNKS_QK; }
    else                                { src = Wk; dst = wkb; loc = cid - 2 * CHUNKS_QK - CHUNKS_W; }
    const float4* p = (const float4*)src + (size_t)loc * 2;
    *(bf16x8*)(dst + (size_t)loc * 8) = pack8(p[0], p[1]);
}

// ---------------------------------------------------------------------------
// proj: Out[b,h,l,dk] = ((X @ Wm^T)[m,n] + bias[n]) * scale, bf16 in/out.
// 128x128 tile, BK=64, 4 waves (wave w -> 64x64 quadrant wr,wc).
// LDS-staged (reg-staging + XOR swizzle idx ^= (row&7)<<3), 2-phase
// prefetch: global loads for tile t+1 issued before compute of tile t.
// grid (M/128=64, N/128=4, 2); z = {Q-proj, K-proj}. 512 blocks, 2/CU.
// ---------------------------------------------------------------------------
__global__ __launch_bounds__(256) void proj_mfma(
    const unsigned short* __restrict__ Xq, const unsigned short* __restrict__ Xk,
    const unsigned short* __restrict__ Wqb, const unsigned short* __restrict__ Wkb,
    const float* __restrict__ bq, const float* __restrict__ bk,
    unsigned short* __restrict__ Qh, unsigned short* __restrict__ Kh)
{
    __shared__ unsigned short Asm[128 * 64];
    __shared__ unsigned short Bsm[128 * 64];

    const int which = blockIdx.z;
    const unsigned short* X  = which ? Xk  : Xq;
    const unsigned short* Wm = which ? Wkb : Wqb;
    const float* bias        = which ? bk  : bq;
    unsigned short* Out      = which ? Kh  : Qh;
    const float scale        = which ? 1.0f : 0.125f;

    const int t  = threadIdx.x;
    const int w  = t >> 6;
    const int l  = t & 63;
    const int wr = w >> 1;
    const int wc = w & 1;
    const int mb = blockIdx.x * 128;
    const int nb = blockIdx.y * 128;
    const int lr = l & 15;
    const int lk = (l >> 4) * 8;

    // per-thread staging slots (4 x 16B for A, same for B)
    int srow[4], scol[4], sswz[4];
#pragma unroll
    for (int i = 0; i < 4; ++i) {
        const int flat = t + i * 256;        // 0..1023
        srow[i] = flat >> 3;                 // 0..127
        scol[i] = (flat & 7) * 8;            // 0..56
        sswz[i] = (srow[i] * 64 + scol[i]) ^ ((srow[i] & 7) << 3);
    }

    bf16x8 ra[4], rb[4];
#pragma unroll
    for (int i = 0; i < 4; ++i) {
        ra[i] = *(const bf16x8*)&X [(size_t)(mb + srow[i]) * DD + scol[i]];
        rb[i] = *(const bf16x8*)&Wm[(size_t)(nb + srow[i]) * DD + scol[i]];
    }

    f32x4 acc[4][4] = {};

    for (int k0 = 0; k0 < DD; k0 += 64) {
        __syncthreads();                     // previous tile's readers done
#pragma unroll
        for (int i = 0; i < 4; ++i) {
            *(bf16x8*)&Asm[sswz[i]] = ra[i];
            *(bf16x8*)&Bsm[sswz[i]] = rb[i];
        }
        // prefetch next K-tile while this one is computed
        if (k0 + 64 < DD) {
#pragma unroll
            for (int i = 0; i < 4; ++i) {
                ra[i] = *(const bf16x8*)&X [(size_t)(mb + srow[i]) * DD + k0 + 64 + scol[i]];
                rb[i] = *(const bf16x8*)&Wm[(size_t)(nb + srow[i]) * DD + k0 + 64 + scol[i]];
            }
        }
        __syncthreads();                     // tile staged

#pragma unroll
        for (int kk = 0; kk < 64; kk += 32) {
            bf16x8 af[4], bfr[4];
#pragma unroll
            for (int mi = 0; mi < 4; ++mi) {
                const int row = wr * 64 + 16 * mi + lr;
                af[mi] = *(const bf16x8*)&Asm[(row * 64 + kk + lk) ^ ((row & 7) << 3)];
            }
#pragma unroll
            for (int ni = 0; ni < 4; ++ni) {
                const int row = wc * 64 + 16 * ni + lr;
                bfr[ni] = *(const bf16x8*)&Bsm[(row * 64 + kk + lk) ^ ((row & 7) << 3)];
            }
#pragma unroll
            for (int mi = 0; mi < 4; ++mi)
#pragma unroll
                for (int ni = 0; ni < 4; ++ni)
                    acc[mi][ni] = __builtin_amdgcn_mfma_f32_16x16x32_bf16(
                        af[mi], bfr[ni], acc[mi][ni], 0, 0, 0);
        }
    }

#pragma unroll
    for (int ni = 0; ni < 4; ++ni) {
        const int n  = nb + wc * 64 + 16 * ni + lr;
        const int h  = n >> 6;
        const int dk = n & 63;
        const float bs = bias[n];
#pragma unroll
        for (int mi = 0; mi < 4; ++mi)
#pragma unroll
            for (int j = 0; j < 4; ++j) {
                const int m    = mb + wr * 64 + 16 * mi + (l >> 4) * 4 + j;
                const int lseq = m >> 2;
                const int bidx = m & 3;
                Out[(((size_t)(bidx * HH + h)) * LL + lseq) * DKK + dk] =
                    f2bf((acc[mi][ni][j] + bs) * scale);
            }
    }
}

// ---------------------------------------------------------------------------
// scorez: Z[bh,q] = sum_k exp( Qh[bh,q] . Kh[bh,k] )   (Q pre-scaled by 1/8)
// ---------------------------------------------------------------------------
__global__ __launch_bounds__(256) void scorez_mfma(
    const unsigned short* __restrict__ Qh, const unsigned short* __restrict__ Kh,
    float* __restrict__ Z)
{
    __shared__ float Zp[4][64];
    const int t  = threadIdx.x;
    const int w  = t >> 6;
    const int l  = t & 63;
    const int bh = blockIdx.y;
    const int qb = blockIdx.x * 64;
    const int lr = l & 15;
    const int lk = (l >> 4) * 8;
    const unsigned short* Qp = Qh + (size_t)bh * LL * DKK;
    const unsigned short* Kp = Kh + (size_t)bh * LL * DKK;

    bf16x8 qa[4][2];
#pragma unroll
    for (int r = 0; r < 4; ++r)
#pragma unroll
        for (int s = 0; s < 2; ++s)
            qa[r][s] = *(const bf16x8*)&Qp[(size_t)(qb + 16 * r + lr) * DKK + 32 * s + lk];

    float zacc[4][4] = {};
    const int k0 = w * 512;
    for (int kt = k0; kt < k0 + 512; kt += 16) {
        const bf16x8 kb0 = *(const bf16x8*)&Kp[(size_t)(kt + lr) * DKK + lk];
        const bf16x8 kb1 = *(const bf16x8*)&Kp[(size_t)(kt + lr) * DKK + 32 + lk];
#pragma unroll
        for (int r = 0; r < 4; ++r) {
            f32x4 acc = {0.f, 0.f, 0.f, 0.f};
            acc = __builtin_amdgcn_mfma_f32_16x16x32_bf16(qa[r][0], kb0, acc, 0, 0, 0);
            acc = __builtin_amdgcn_mfma_f32_16x16x32_bf16(qa[r][1], kb1, acc, 0, 0, 0);
#pragma unroll
            for (int j = 0; j < 4; ++j)
                zacc[r][j] += __expf(acc[j]);
        }
    }

#pragma unroll
    for (int m = 8; m >= 1; m >>= 1)
#pragma unroll
        for (int r = 0; r < 4; ++r)
#pragma unroll
            for (int j = 0; j < 4; ++j)
                zacc[r][j] += __shfl_xor(zacc[r][j], m, 64);

    if (lr == 0) {
#pragma unroll
        for (int r = 0; r < 4; ++r)
#pragma unroll
            for (int j = 0; j < 4; ++j)
                Zp[w][16 * r + (l >> 4) * 4 + j] = zacc[r][j];
    }
    __syncthreads();
    if (t < 64)
        Z[(size_t)bh * LL + qb + t] = Zp[0][t] + Zp[1][t] + Zp[2][t] + Zp[3][t];
}

// ---------------------------------------------------------------------------
// weights: one WAVE per (b,q). Computes normalized band weights; writes them
// compact to wgtbuf AND scatters them into the pre-zeroed dense wout row.
// ---------------------------------------------------------------------------
__global__ __launch_bounds__(256) void weights_kernel(
    const unsigned short* __restrict__ Qh, const unsigned short* __restrict__ Kh,
    const float* __restrict__ Z, float* __restrict__ wgtbuf,
    float* __restrict__ wout)
{
    const int t = threadIdx.x;
    const int w = t >> 6;
    const int l = t & 63;
    const int idx = blockIdx.x * 4 + w;       // idx = b*L + q
    const int b = idx >> 11;
    const int q = idx & 2047;
    const int h = l >> 3;
    const int jslot = l & 7;

    bf16x8 qv[8];
    {
        const bf16x8* qp = (const bf16x8*)&Qh[(((size_t)b * HH + h) * LL + q) * DKK];
#pragma unroll
        for (int i = 0; i < 8; ++i) qv[i] = qp[i];
    }
    const float zinv = 1.0f / Z[((size_t)b * HH + h) * LL + q];

    float e[4];
#pragma unroll
    for (int c = 0; c < 4; ++c) {
        const int j = jslot + 8 * c;
        const int k = q - WBAND + j;
        float a = 0.f;
        if (j < NBAND && k >= 0 && k < LL) {
            const bf16x8* kp = (const bf16x8*)&Kh[(((size_t)b * HH + h) * LL + k) * DKK];
            float s = 0.f;
#pragma unroll
            for (int i = 0; i < 8; ++i) {
                const bf16x8 ka = kp[i];
#pragma unroll
                for (int ee = 0; ee < 8; ++ee)
                    s += bf2f((unsigned short)qv[i][ee]) * bf2f((unsigned short)ka[ee]);
            }
            a = __expf(s) * zinv;
        }
        e[c] = a;
    }

    // sum over heads (lane bits 3,4,5)
#pragma unroll
    for (int m = 8; m <= 32; m <<= 1)
#pragma unroll
        for (int c = 0; c < 4; ++c)
            e[c] += __shfl_xor(e[c], m, 64);

    // * dist, then band-sum over jslot (lane bits 0,1,2)
    float att[4];
    float part = 0.f;
#pragma unroll
    for (int c = 0; c < 4; ++c) {
        const int j = jslot + 8 * c;
        const float dd = (float)(j - WBAND);
        att[c] = (j < NBAND) ? e[c] * __expf(-0.5f * dd * dd) : 0.f;
        part += att[c];
    }
#pragma unroll
    for (int m = 1; m <= 4; m <<= 1)
        part += __shfl_xor(part, m, 64);
    const float winv = 1.0f / part;

    if (h == 0) {
        float* wrow = &wout[((size_t)b * LL + q) * LL];
#pragma unroll
        for (int c = 0; c < 4; ++c) {
            const int j = jslot + 8 * c;
            if (j < NBAND) {
                const float wv = att[c] * winv;
                wgtbuf[(size_t)idx * 32 + j] = wv;
                const int k = q - WBAND + j;
                if (k >= 0 && k < LL) wrow[k] = wv;
            }
        }
    }
}

// ---------------------------------------------------------------------------
// out: grid (L/8, B). Per block: 8 q rows. Register sliding window over v.
// ---------------------------------------------------------------------------
__global__ __launch_bounds__(256) void out_kernel(
    const float* __restrict__ wgtbuf, const float* __restrict__ v,
    float* __restrict__ out)
{
    __shared__ float lw[8][NBAND];
    const int t  = threadIdx.x;
    const int q0 = blockIdx.x * 8;
    const int b  = blockIdx.y;

    if (t < 8 * NBAND) {
        const int qq = t / NBAND;
        const int j  = t - qq * NBAND;
        lw[qq][j] = wgtbuf[((size_t)b * LL + q0 + qq) * 32 + j];
    }
    __syncthreads();

    const int qsub = t >> 7;
    const int d4   = t & 127;
    const int qs   = q0 + qsub * 4;
    const int kbase = qs - WBAND;
    f32x4 acc[4] = {{0,0,0,0},{0,0,0,0},{0,0,0,0},{0,0,0,0}};
#pragma unroll
    for (int kk = 0; kk < 28; ++kk) {
        const int k = kbase + kk;
        f32x4 vv = {0.f, 0.f, 0.f, 0.f};
        if (k >= 0 && k < LL)
            vv = *(const f32x4*)&v[((size_t)k * BB + b) * DD + d4 * 4];
#pragma unroll
        for (int qi = 0; qi < 4; ++qi) {
            const int j = kk - qi;
            if (j >= 0 && j < NBAND) {
                const float wv = lw[qsub * 4 + qi][j];
                acc[qi][0] += wv * vv[0]; acc[qi][1] += wv * vv[1];
                acc[qi][2] += wv * vv[2]; acc[qi][3] += wv * vv[3];
            }
        }
    }
#pragma unroll
    for (int qi = 0; qi < 4; ++qi) {
        const int q = qs + qi;
        __builtin_nontemporal_store(acc[qi],
            (f32x4*)&out[((size_t)q * BB + b) * DD + d4 * 4]);
    }
}

// ---------------------------------------------------------------------------
extern "C" void kernel_launch(void* const* d_in, const int* in_sizes, int n_in,
                              void* d_out, int out_size, void* d_ws, size_t ws_size,
                              hipStream_t stream) {
    const float* q  = (const float*)d_in[0];
    const float* k  = (const float*)d_in[1];
    const float* v  = (const float*)d_in[2];
    const float* Wq = (const float*)d_in[3];
    const float* bq = (const float*)d_in[4];
    const float* Wk = (const float*)d_in[5];
    const float* bk = (const float*)d_in[6];

    float* out  = (float*)d_out;                       // [L,B,D]
    float* wout = out + (size_t)LL * BB * DD;          // [B,L,L]

    unsigned short* Qh  = (unsigned short*)d_ws;                // bf16 [B,H,L,DK] 8 MB
    unsigned short* Kh  = Qh  + (size_t)BB * HH * LL * DKK;     // bf16 8 MB
    unsigned short* qbf = Kh  + (size_t)BB * HH * LL * DKK;     // bf16 [L*B][D] 8 MB
    unsigned short* kbf = qbf + (size_t)LL * BB * DD;           // bf16 8 MB
    unsigned short* wqb = kbf + (size_t)LL * BB * DD;           // bf16 [D][D] 0.5 MB
    unsigned short* wkb = wqb + (size_t)DD * DD;                // bf16 0.5 MB
    float* Z      = (float*)(wkb + (size_t)DD * DD);            // [B*H*L] 256 KB
    float* wgtbuf = Z + (size_t)BB * HH * LL;                   // [B*L][32] 1 MB

    // zero dense wout (band values scattered in by weights_kernel)
    (void)hipMemsetAsync(wout, 0, (size_t)BB * LL * LL * sizeof(float), stream);

    cvt_kernel<<<CHUNKS_TOT / 256, 256, 0, stream>>>(q, k, Wq, Wk, qbf, kbf, wqb, wkb);

    proj_mfma<<<dim3(LL * BB / 128, DD / 128, 2), 256, 0, stream>>>(
        qbf, kbf, wqb, wkb, bq, bk, Qh, Kh);

    scorez_mfma<<<dim3(LL / 64, BB * HH), 256, 0, stream>>>(Qh, Kh, Z);

    weights_kernel<<<BB * LL / 4, 256, 0, stream>>>(Qh, Kh, Z, wgtbuf, wout);

    out_kernel<<<dim3(LL / 8, BB), 256, 0, stream>>>(wgtbuf, v, out);
}

// Round 8
// 125.900 us; speedup vs baseline: 1.5504x; 1.0342x over previous
//
#include <hip/hip_runtime.h>

#define LL   2048
#define BB   4
#define DD   512
#define HH   8
#define DKK  64
#define WBAND 12
#define NBAND 25   // 2*WBAND+1

typedef __attribute__((ext_vector_type(8))) short  bf16x8;
typedef __attribute__((ext_vector_type(4))) float  f32x4;

static __device__ __forceinline__ float bf2f(unsigned short u) {
    union { unsigned int i; float f; } c; c.i = ((unsigned int)u) << 16; return c.f;
}
static __device__ __forceinline__ unsigned short f2bf(float f) {
    union { float f; unsigned int i; } c; c.f = f;
    unsigned int x = c.i;
    return (unsigned short)((x + 0x7fffu + ((x >> 16) & 1u)) >> 16);  // RNE
}
static __device__ __forceinline__ bf16x8 pack8(float4 x0, float4 x1) {
    bf16x8 r;
    r[0] = (short)f2bf(x0.x); r[1] = (short)f2bf(x0.y);
    r[2] = (short)f2bf(x0.z); r[3] = (short)f2bf(x0.w);
    r[4] = (short)f2bf(x1.x); r[5] = (short)f2bf(x1.y);
    r[6] = (short)f2bf(x1.z); r[7] = (short)f2bf(x1.w);
    return r;
}

// ---------------------------------------------------------------------------
// cvt: fp32 -> bf16 for q, k (L*B*D each) and Wq, Wk (D*D each).
// ---------------------------------------------------------------------------
#define CHUNKS_QK  524288    // (L*B*D)/8
#define CHUNKS_W   32768     // (D*D)/8
#define CHUNKS_TOT (2*CHUNKS_QK + 2*CHUNKS_W)

__global__ __launch_bounds__(256) void cvt_kernel(
    const float* __restrict__ q, const float* __restrict__ k,
    const float* __restrict__ Wq, const float* __restrict__ Wk,
    unsigned short* __restrict__ qb, unsigned short* __restrict__ kb,
    unsigned short* __restrict__ wqb, unsigned short* __restrict__ wkb)
{
    const int cid = blockIdx.x * 256 + threadIdx.x;
    const float* src;
    unsigned short* dst;
    int loc;
    if (cid < CHUNKS_QK)                { src = q;  dst = qb;  loc = cid; }
    else if (cid < 2 * CHUNKS_QK)       { src = k;  dst = kb;  loc = cid - CHUNKS_QK; }
    else if (cid < 2 * CHUNKS_QK + CHUNKS_W) { src = Wq; dst = wqb; loc = cid - 2 * CHUNKS_QK; }
    else                                { src = Wk; dst = wkb; loc = cid - 2 * CHUNKS_QK - CHUNKS_W; }
    const float4* p = (const float4*)src + (size_t)loc * 2;
    *(bf16x8*)(dst + (size_t)loc * 8) = pack8(p[0], p[1]);
}

// ---------------------------------------------------------------------------
// proj: Out[b,h,l,dk] = ((X @ Wm^T)[m,n] + bias[n]) * scale, bf16 in/out.
// 128x128 tile, BK=64, 4 waves; LDS-staged with XOR swizzle; reg prefetch.
// ---------------------------------------------------------------------------
__global__ __launch_bounds__(256) void proj_mfma(
    const unsigned short* __restrict__ Xq, const unsigned short* __restrict__ Xk,
    const unsigned short* __restrict__ Wqb, const unsigned short* __restrict__ Wkb,
    const float* __restrict__ bq, const float* __restrict__ bk,
    unsigned short* __restrict__ Qh, unsigned short* __restrict__ Kh)
{
    __shared__ unsigned short Asm[128 * 64];
    __shared__ unsigned short Bsm[128 * 64];

    const int which = blockIdx.z;
    const unsigned short* X  = which ? Xk  : Xq;
    const unsigned short* Wm = which ? Wkb : Wqb;
    const float* bias        = which ? bk  : bq;
    unsigned short* Out      = which ? Kh  : Qh;
    const float scale        = which ? 1.0f : 0.125f;

    const int t  = threadIdx.x;
    const int w  = t >> 6;
    const int l  = t & 63;
    const int wr = w >> 1;
    const int wc = w & 1;
    const int mb = blockIdx.x * 128;
    const int nb = blockIdx.y * 128;
    const int lr = l & 15;
    const int lk = (l >> 4) * 8;

    int srow[4], scol[4], sswz[4];
#pragma unroll
    for (int i = 0; i < 4; ++i) {
        const int flat = t + i * 256;        // 0..1023
        srow[i] = flat >> 3;                 // 0..127
        scol[i] = (flat & 7) * 8;            // 0..56
        sswz[i] = (srow[i] * 64 + scol[i]) ^ ((srow[i] & 7) << 3);
    }

    bf16x8 ra[4], rb[4];
#pragma unroll
    for (int i = 0; i < 4; ++i) {
        ra[i] = *(const bf16x8*)&X [(size_t)(mb + srow[i]) * DD + scol[i]];
        rb[i] = *(const bf16x8*)&Wm[(size_t)(nb + srow[i]) * DD + scol[i]];
    }

    f32x4 acc[4][4] = {};

    for (int k0 = 0; k0 < DD; k0 += 64) {
        __syncthreads();
#pragma unroll
        for (int i = 0; i < 4; ++i) {
            *(bf16x8*)&Asm[sswz[i]] = ra[i];
            *(bf16x8*)&Bsm[sswz[i]] = rb[i];
        }
        if (k0 + 64 < DD) {
#pragma unroll
            for (int i = 0; i < 4; ++i) {
                ra[i] = *(const bf16x8*)&X [(size_t)(mb + srow[i]) * DD + k0 + 64 + scol[i]];
                rb[i] = *(const bf16x8*)&Wm[(size_t)(nb + srow[i]) * DD + k0 + 64 + scol[i]];
            }
        }
        __syncthreads();

#pragma unroll
        for (int kk = 0; kk < 64; kk += 32) {
            bf16x8 af[4], bfr[4];
#pragma unroll
            for (int mi = 0; mi < 4; ++mi) {
                const int row = wr * 64 + 16 * mi + lr;
                af[mi] = *(const bf16x8*)&Asm[(row * 64 + kk + lk) ^ ((row & 7) << 3)];
            }
#pragma unroll
            for (int ni = 0; ni < 4; ++ni) {
                const int row = wc * 64 + 16 * ni + lr;
                bfr[ni] = *(const bf16x8*)&Bsm[(row * 64 + kk + lk) ^ ((row & 7) << 3)];
            }
#pragma unroll
            for (int mi = 0; mi < 4; ++mi)
#pragma unroll
                for (int ni = 0; ni < 4; ++ni)
                    acc[mi][ni] = __builtin_amdgcn_mfma_f32_16x16x32_bf16(
                        af[mi], bfr[ni], acc[mi][ni], 0, 0, 0);
        }
    }

#pragma unroll
    for (int ni = 0; ni < 4; ++ni) {
        const int n  = nb + wc * 64 + 16 * ni + lr;
        const int h  = n >> 6;
        const int dk = n & 63;
        const float bs = bias[n];
#pragma unroll
        for (int mi = 0; mi < 4; ++mi)
#pragma unroll
            for (int j = 0; j < 4; ++j) {
                const int m    = mb + wr * 64 + 16 * mi + (l >> 4) * 4 + j;
                const int lseq = m >> 2;
                const int bidx = m & 3;
                Out[(((size_t)(bidx * HH + h)) * LL + lseq) * DKK + dk] =
                    f2bf((acc[mi][ni][j] + bs) * scale);
            }
    }
}

// ---------------------------------------------------------------------------
// scorez: Z[bh,q] = sum_k exp( Qh[bh,q] . Kh[bh,k] )   (Q pre-scaled by 1/8)
// ---------------------------------------------------------------------------
__global__ __launch_bounds__(256) void scorez_mfma(
    const unsigned short* __restrict__ Qh, const unsigned short* __restrict__ Kh,
    float* __restrict__ Z)
{
    __shared__ float Zp[4][64];
    const int t  = threadIdx.x;
    const int w  = t >> 6;
    const int l  = t & 63;
    const int bh = blockIdx.y;
    const int qb = blockIdx.x * 64;
    const int lr = l & 15;
    const int lk = (l >> 4) * 8;
    const unsigned short* Qp = Qh + (size_t)bh * LL * DKK;
    const unsigned short* Kp = Kh + (size_t)bh * LL * DKK;

    bf16x8 qa[4][2];
#pragma unroll
    for (int r = 0; r < 4; ++r)
#pragma unroll
        for (int s = 0; s < 2; ++s)
            qa[r][s] = *(const bf16x8*)&Qp[(size_t)(qb + 16 * r + lr) * DKK + 32 * s + lk];

    float zacc[4][4] = {};
    const int k0 = w * 512;
    for (int kt = k0; kt < k0 + 512; kt += 16) {
        const bf16x8 kb0 = *(const bf16x8*)&Kp[(size_t)(kt + lr) * DKK + lk];
        const bf16x8 kb1 = *(const bf16x8*)&Kp[(size_t)(kt + lr) * DKK + 32 + lk];
#pragma unroll
        for (int r = 0; r < 4; ++r) {
            f32x4 acc = {0.f, 0.f, 0.f, 0.f};
            acc = __builtin_amdgcn_mfma_f32_16x16x32_bf16(qa[r][0], kb0, acc, 0, 0, 0);
            acc = __builtin_amdgcn_mfma_f32_16x16x32_bf16(qa[r][1], kb1, acc, 0, 0, 0);
#pragma unroll
            for (int j = 0; j < 4; ++j)
                zacc[r][j] += __expf(acc[j]);
        }
    }

#pragma unroll
    for (int m = 8; m >= 1; m >>= 1)
#pragma unroll
        for (int r = 0; r < 4; ++r)
#pragma unroll
            for (int j = 0; j < 4; ++j)
                zacc[r][j] += __shfl_xor(zacc[r][j], m, 64);

    if (lr == 0) {
#pragma unroll
        for (int r = 0; r < 4; ++r)
#pragma unroll
            for (int j = 0; j < 4; ++j)
                Zp[w][16 * r + (l >> 4) * 4 + j] = zacc[r][j];
    }
    __syncthreads();
    if (t < 64)
        Z[(size_t)bh * LL + qb + t] = Zp[0][t] + Zp[1][t] + Zp[2][t] + Zp[3][t];
}

// ---------------------------------------------------------------------------
// weights: one WAVE per (b,q). Computes normalized band weights -> wgtbuf.
// ---------------------------------------------------------------------------
__global__ __launch_bounds__(256) void weights_kernel(
    const unsigned short* __restrict__ Qh, const unsigned short* __restrict__ Kh,
    const float* __restrict__ Z, float* __restrict__ wgtbuf)
{
    const int t = threadIdx.x;
    const int w = t >> 6;
    const int l = t & 63;
    const int idx = blockIdx.x * 4 + w;       // idx = b*L + q
    const int b = idx >> 11;
    const int q = idx & 2047;
    const int h = l >> 3;
    const int jslot = l & 7;

    bf16x8 qv[8];
    {
        const bf16x8* qp = (const bf16x8*)&Qh[(((size_t)b * HH + h) * LL + q) * DKK];
#pragma unroll
        for (int i = 0; i < 8; ++i) qv[i] = qp[i];
    }
    const float zinv = 1.0f / Z[((size_t)b * HH + h) * LL + q];

    float e[4];
#pragma unroll
    for (int c = 0; c < 4; ++c) {
        const int j = jslot + 8 * c;
        const int k = q - WBAND + j;
        float a = 0.f;
        if (j < NBAND && k >= 0 && k < LL) {
            const bf16x8* kp = (const bf16x8*)&Kh[(((size_t)b * HH + h) * LL + k) * DKK];
            float s = 0.f;
#pragma unroll
            for (int i = 0; i < 8; ++i) {
                const bf16x8 ka = kp[i];
#pragma unroll
                for (int ee = 0; ee < 8; ++ee)
                    s += bf2f((unsigned short)qv[i][ee]) * bf2f((unsigned short)ka[ee]);
            }
            a = __expf(s) * zinv;
        }
        e[c] = a;
    }

#pragma unroll
    for (int m = 8; m <= 32; m <<= 1)
#pragma unroll
        for (int c = 0; c < 4; ++c)
            e[c] += __shfl_xor(e[c], m, 64);

    float att[4];
    float part = 0.f;
#pragma unroll
    for (int c = 0; c < 4; ++c) {
        const int j = jslot + 8 * c;
        const float dd = (float)(j - WBAND);
        att[c] = (j < NBAND) ? e[c] * __expf(-0.5f * dd * dd) : 0.f;
        part += att[c];
    }
#pragma unroll
    for (int m = 1; m <= 4; m <<= 1)
        part += __shfl_xor(part, m, 64);
    const float winv = 1.0f / part;

    if (h == 0) {
#pragma unroll
        for (int c = 0; c < 4; ++c) {
            const int j = jslot + 8 * c;
            if (j < NBAND)
                wgtbuf[(size_t)idx * 32 + j] = att[c] * winv;
        }
    }
}

// ---------------------------------------------------------------------------
// woutout: grid (L/8, B). Per block: 8 q rows for one b.
//   phase 1: LDS-load wgt[8][25]
//   phase 2: stream FULL wout rows (zeros + band) with NT f32x4 stores
//   phase 3: out[q,b,:] via register sliding window over 28 v rows
// Replaces the 67 MB memset (rocclr fill ran at only 1.4 TB/s).
// ---------------------------------------------------------------------------
__global__ __launch_bounds__(256) void woutout_kernel(
    const float* __restrict__ wgtbuf, const float* __restrict__ v,
    float* __restrict__ out, float* __restrict__ wout)
{
    __shared__ float lw[8][NBAND];
    const int t  = threadIdx.x;
    const int q0 = blockIdx.x * 8;
    const int b  = blockIdx.y;

    if (t < 8 * NBAND) {
        const int qq = t / NBAND;
        const int j  = t - qq * NBAND;
        lw[qq][j] = wgtbuf[((size_t)b * LL + q0 + qq) * 32 + j];
    }
    __syncthreads();

    // ---- wout: 8 rows x 512 f32x4 = 4096 f4, 16 per thread ----
#pragma unroll
    for (int r = 0; r < 16; ++r) {
        const int flat = t + 256 * r;
        const int qq = flat >> 9;
        const int c4 = flat & 511;
        const int q  = q0 + qq;
        const int c  = c4 * 4;
        f32x4 vw = {0.f, 0.f, 0.f, 0.f};
        const int dlo = c - q + WBAND;          // j of element e=0
        if (dlo >= -3 && dlo < NBAND) {
#pragma unroll
            for (int e = 0; e < 4; ++e) {
                const int d = dlo + e;
                if (d >= 0 && d < NBAND) vw[e] = lw[qq][d];
            }
        }
        __builtin_nontemporal_store(vw, (f32x4*)&wout[((size_t)b * LL + q) * LL + c]);
    }

    // ---- out: thread t -> qsub = t>>7 (4 q each), d4 = t&127 ----
    {
        const int qsub = t >> 7;
        const int d4   = t & 127;
        const int qs   = q0 + qsub * 4;
        const int kbase = qs - WBAND;
        f32x4 acc[4] = {{0,0,0,0},{0,0,0,0},{0,0,0,0},{0,0,0,0}};
#pragma unroll
        for (int kk = 0; kk < 28; ++kk) {
            const int k = kbase + kk;
            f32x4 vv = {0.f, 0.f, 0.f, 0.f};
            if (k >= 0 && k < LL)
                vv = *(const f32x4*)&v[((size_t)k * BB + b) * DD + d4 * 4];
#pragma unroll
            for (int qi = 0; qi < 4; ++qi) {
                const int j = kk - qi;
                if (j >= 0 && j < NBAND) {
                    const float wv = lw[qsub * 4 + qi][j];
                    acc[qi][0] += wv * vv[0]; acc[qi][1] += wv * vv[1];
                    acc[qi][2] += wv * vv[2]; acc[qi][3] += wv * vv[3];
                }
            }
        }
#pragma unroll
        for (int qi = 0; qi < 4; ++qi) {
            const int q = qs + qi;
            __builtin_nontemporal_store(acc[qi],
                (f32x4*)&out[((size_t)q * BB + b) * DD + d4 * 4]);
        }
    }
}

// ---------------------------------------------------------------------------
extern "C" void kernel_launch(void* const* d_in, const int* in_sizes, int n_in,
                              void* d_out, int out_size, void* d_ws, size_t ws_size,
                              hipStream_t stream) {
    const float* q  = (const float*)d_in[0];
    const float* k  = (const float*)d_in[1];
    const float* v  = (const float*)d_in[2];
    const float* Wq = (const float*)d_in[3];
    const float* bq = (const float*)d_in[4];
    const float* Wk = (const float*)d_in[5];
    const float* bk = (const float*)d_in[6];

    float* out  = (float*)d_out;                       // [L,B,D]
    float* wout = out + (size_t)LL * BB * DD;          // [B,L,L]

    unsigned short* Qh  = (unsigned short*)d_ws;                // bf16 [B,H,L,DK] 8 MB
    unsigned short* Kh  = Qh  + (size_t)BB * HH * LL * DKK;     // bf16 8 MB
    unsigned short* qbf = Kh  + (size_t)BB * HH * LL * DKK;     // bf16 [L*B][D] 8 MB
    unsigned short* kbf = qbf + (size_t)LL * BB * DD;           // bf16 8 MB
    unsigned short* wqb = kbf + (size_t)LL * BB * DD;           // bf16 [D][D] 0.5 MB
    unsigned short* wkb = wqb + (size_t)DD * DD;                // bf16 0.5 MB
    float* Z      = (float*)(wkb + (size_t)DD * DD);            // [B*H*L] 256 KB
    float* wgtbuf = Z + (size_t)BB * HH * LL;                   // [B*L][32] 1 MB

    cvt_kernel<<<CHUNKS_TOT / 256, 256, 0, stream>>>(q, k, Wq, Wk, qbf, kbf, wqb, wkb);

    proj_mfma<<<dim3(LL * BB / 128, DD / 128, 2), 256, 0, stream>>>(
        qbf, kbf, wqb, wkb, bq, bk, Qh, Kh);

    scorez_mfma<<<dim3(LL / 64, BB * HH), 256, 0, stream>>>(Qh, Kh, Z);

    weights_kernel<<<BB * LL / 4, 256, 0, stream>>>(Qh, Kh, Z, wgtbuf);

    woutout_kernel<<<dim3(LL / 8, BB), 256, 0, stream>>>(wgtbuf, v, out, wout);
}

// Round 9
// 124.962 us; speedup vs baseline: 1.5620x; 1.0075x over previous
//
#include <hip/hip_runtime.h>
#include <hip/hip_bf16.h>

#define LL   2048
#define BB   4
#define DD   512
#define HH   8
#define DKK  64
#define WBAND 12
#define NBAND 25   // 2*WBAND+1

typedef __attribute__((ext_vector_type(8))) short  bf16x8;
typedef __attribute__((ext_vector_type(4))) float  f32x4;

static __device__ __forceinline__ float bf2f(unsigned short u) {
    union { unsigned int i; float f; } c; c.i = ((unsigned int)u) << 16; return c.f;
}
// manual RNE (used in epilogue, cold path)
static __device__ __forceinline__ unsigned short f2bf(float f) {
    union { float f; unsigned int i; } c; c.f = f;
    unsigned int x = c.i;
    return (unsigned short)((x + 0x7fffu + ((x >> 16) & 1u)) >> 16);
}
// compiler-fused cvt (hot staging path; pairs become v_cvt_pk_bf16_f32)
static __device__ __forceinline__ unsigned short f2bf_rn(float f) {
    __hip_bfloat16 h = __float2bfloat16(f);
    return reinterpret_cast<unsigned short&>(h);
}
static __device__ __forceinline__ bf16x8 pack8(float4 x0, float4 x1) {
    bf16x8 r;
    r[0] = (short)f2bf_rn(x0.x); r[1] = (short)f2bf_rn(x0.y);
    r[2] = (short)f2bf_rn(x0.z); r[3] = (short)f2bf_rn(x0.w);
    r[4] = (short)f2bf_rn(x1.x); r[5] = (short)f2bf_rn(x1.y);
    r[6] = (short)f2bf_rn(x1.z); r[7] = (short)f2bf_rn(x1.w);
    return r;
}

#define WOUT_F4   4194304   // B*L*L/4
#define ZP_PROJ   1703936   // 13 * 512*256  (f4 covered by proj)

// ---------------------------------------------------------------------------
// proj: Out[b,h,l,dk] = ((X @ Wm^T)[m,n] + bias[n]) * scale.
// Reads fp32 X/Wm directly; converts to bf16 in the LDS staging path.
// 128x128 tile, BK=64, 4 waves; XOR-swizzled LDS; fp32 reg prefetch.
// Also zero-writes f4 slice [0, ZP_PROJ) of wout (overlapped with compute).
// ---------------------------------------------------------------------------
__global__ __launch_bounds__(256) void proj_mfma(
    const float* __restrict__ Xq, const float* __restrict__ Xk,
    const float* __restrict__ Wqf, const float* __restrict__ Wkf,
    const float* __restrict__ bq, const float* __restrict__ bk,
    unsigned short* __restrict__ Qh, unsigned short* __restrict__ Kh,
    float* __restrict__ wout)
{
    __shared__ unsigned short Asm[128 * 64];
    __shared__ unsigned short Bsm[128 * 64];

    const int which = blockIdx.z;
    const float* X   = which ? Xk  : Xq;
    const float* Wm  = which ? Wkf : Wqf;
    const float* bias = which ? bk : bq;
    unsigned short* Out = which ? Kh : Qh;
    const float scale   = which ? 1.0f : 0.125f;

    const int t  = threadIdx.x;
    const int w  = t >> 6;
    const int l  = t & 63;
    const int wr = w >> 1;
    const int wc = w & 1;
    const int mb = blockIdx.x * 128;
    const int nb = blockIdx.y * 128;
    const int lr = l & 15;
    const int lk = (l >> 4) * 8;

    int srow[4], scol[4], sswz[4];
#pragma unroll
    for (int i = 0; i < 4; ++i) {
        const int flat = t + i * 256;        // 0..1023
        srow[i] = flat >> 3;                 // 0..127
        scol[i] = (flat & 7) * 8;            // 0..56 (in elements)
        sswz[i] = (srow[i] * 64 + scol[i]) ^ ((srow[i] & 7) << 3);
    }

    // issue first prefetch (latency-critical), fp32
    float4 ra[4][2], rb[4][2];
#pragma unroll
    for (int i = 0; i < 4; ++i) {
        const float* pa = &X [(size_t)(mb + srow[i]) * DD + scol[i]];
        const float* pb = &Wm[(size_t)(nb + srow[i]) * DD + scol[i]];
        ra[i][0] = *(const float4*)pa; ra[i][1] = *(const float4*)(pa + 4);
        rb[i][0] = *(const float4*)pb; rb[i][1] = *(const float4*)(pb + 4);
    }

    // zero-head: 13 f32x4 zeros into wout slice (fire-and-forget, drains under MFMA)
    {
        const int fb  = (blockIdx.z * 4 + blockIdx.y) * 64 + blockIdx.x;  // 0..511
        const int gid = fb * 256 + t;                                     // 0..131071
        const f32x4 zz = {0.f, 0.f, 0.f, 0.f};
#pragma unroll
        for (int i = 0; i < 13; ++i) {
            const size_t idx = (size_t)gid + (size_t)i * 131072;          // < ZP_PROJ
            __builtin_nontemporal_store(zz, (f32x4*)&wout[idx * 4]);
        }
    }

    f32x4 acc[4][4] = {};

    for (int k0 = 0; k0 < DD; k0 += 64) {
        __syncthreads();
#pragma unroll
        for (int i = 0; i < 4; ++i) {
            *(bf16x8*)&Asm[sswz[i]] = pack8(ra[i][0], ra[i][1]);
            *(bf16x8*)&Bsm[sswz[i]] = pack8(rb[i][0], rb[i][1]);
        }
        if (k0 + 64 < DD) {
#pragma unroll
            for (int i = 0; i < 4; ++i) {
                const float* pa = &X [(size_t)(mb + srow[i]) * DD + k0 + 64 + scol[i]];
                const float* pb = &Wm[(size_t)(nb + srow[i]) * DD + k0 + 64 + scol[i]];
                ra[i][0] = *(const float4*)pa; ra[i][1] = *(const float4*)(pa + 4);
                rb[i][0] = *(const float4*)pb; rb[i][1] = *(const float4*)(pb + 4);
            }
        }
        __syncthreads();

#pragma unroll
        for (int kk = 0; kk < 64; kk += 32) {
            bf16x8 af[4], bfr[4];
#pragma unroll
            for (int mi = 0; mi < 4; ++mi) {
                const int row = wr * 64 + 16 * mi + lr;
                af[mi] = *(const bf16x8*)&Asm[(row * 64 + kk + lk) ^ ((row & 7) << 3)];
            }
#pragma unroll
            for (int ni = 0; ni < 4; ++ni) {
                const int row = wc * 64 + 16 * ni + lr;
                bfr[ni] = *(const bf16x8*)&Bsm[(row * 64 + kk + lk) ^ ((row & 7) << 3)];
            }
#pragma unroll
            for (int mi = 0; mi < 4; ++mi)
#pragma unroll
                for (int ni = 0; ni < 4; ++ni)
                    acc[mi][ni] = __builtin_amdgcn_mfma_f32_16x16x32_bf16(
                        af[mi], bfr[ni], acc[mi][ni], 0, 0, 0);
        }
    }

#pragma unroll
    for (int ni = 0; ni < 4; ++ni) {
        const int n  = nb + wc * 64 + 16 * ni + lr;
        const int h  = n >> 6;
        const int dk = n & 63;
        const float bs = bias[n];
#pragma unroll
        for (int mi = 0; mi < 4; ++mi)
#pragma unroll
            for (int j = 0; j < 4; ++j) {
                const int m    = mb + wr * 64 + 16 * mi + (l >> 4) * 4 + j;
                const int lseq = m >> 2;
                const int bidx = m & 3;
                Out[(((size_t)(bidx * HH + h)) * LL + lseq) * DKK + dk] =
                    f2bf((acc[mi][ni][j] + bs) * scale);
            }
    }
}

// ---------------------------------------------------------------------------
// scorez: Z[bh,q] = sum_k exp( Qh[bh,q] . Kh[bh,k] )   (Q pre-scaled by 1/8)
// Also zero-writes f4 slice [ZP_PROJ, WOUT_F4) of wout.
// ---------------------------------------------------------------------------
__global__ __launch_bounds__(256) void scorez_mfma(
    const unsigned short* __restrict__ Qh, const unsigned short* __restrict__ Kh,
    float* __restrict__ Z, float* __restrict__ wout)
{
    __shared__ float Zp[4][64];
    const int t  = threadIdx.x;
    const int w  = t >> 6;
    const int l  = t & 63;
    const int bh = blockIdx.y;
    const int qb = blockIdx.x * 64;
    const int lr = l & 15;
    const int lk = (l >> 4) * 8;
    const unsigned short* Qp = Qh + (size_t)bh * LL * DKK;
    const unsigned short* Kp = Kh + (size_t)bh * LL * DKK;

    // zero-head: 10 f32x4 zeros (last chunk bounds-checked)
    {
        const int fb  = blockIdx.y * 32 + blockIdx.x;   // 0..1023
        const int gid = fb * 256 + t;                   // 0..262143
        const f32x4 zz = {0.f, 0.f, 0.f, 0.f};
#pragma unroll
        for (int i = 0; i < 10; ++i) {
            const size_t idx = (size_t)ZP_PROJ + (size_t)gid + (size_t)i * 262144;
            if (idx < WOUT_F4)
                __builtin_nontemporal_store(zz, (f32x4*)&wout[idx * 4]);
        }
    }

    bf16x8 qa[4][2];
#pragma unroll
    for (int r = 0; r < 4; ++r)
#pragma unroll
        for (int s = 0; s < 2; ++s)
            qa[r][s] = *(const bf16x8*)&Qp[(size_t)(qb + 16 * r + lr) * DKK + 32 * s + lk];

    float zacc[4][4] = {};
    const int k0 = w * 512;
    for (int kt = k0; kt < k0 + 512; kt += 16) {
        const bf16x8 kb0 = *(const bf16x8*)&Kp[(size_t)(kt + lr) * DKK + lk];
        const bf16x8 kb1 = *(const bf16x8*)&Kp[(size_t)(kt + lr) * DKK + 32 + lk];
#pragma unroll
        for (int r = 0; r < 4; ++r) {
            f32x4 acc = {0.f, 0.f, 0.f, 0.f};
            acc = __builtin_amdgcn_mfma_f32_16x16x32_bf16(qa[r][0], kb0, acc, 0, 0, 0);
            acc = __builtin_amdgcn_mfma_f32_16x16x32_bf16(qa[r][1], kb1, acc, 0, 0, 0);
#pragma unroll
            for (int j = 0; j < 4; ++j)
                zacc[r][j] += __expf(acc[j]);
        }
    }

#pragma unroll
    for (int m = 8; m >= 1; m >>= 1)
#pragma unroll
        for (int r = 0; r < 4; ++r)
#pragma unroll
            for (int j = 0; j < 4; ++j)
                zacc[r][j] += __shfl_xor(zacc[r][j], m, 64);

    if (lr == 0) {
#pragma unroll
        for (int r = 0; r < 4; ++r)
#pragma unroll
            for (int j = 0; j < 4; ++j)
                Zp[w][16 * r + (l >> 4) * 4 + j] = zacc[r][j];
    }
    __syncthreads();
    if (t < 64)
        Z[(size_t)bh * LL + qb + t] = Zp[0][t] + Zp[1][t] + Zp[2][t] + Zp[3][t];
}

// ---------------------------------------------------------------------------
// weights: one WAVE per (b,q): band weights -> wgtbuf + scatter into the
// (already-zeroed) dense wout row.
// ---------------------------------------------------------------------------
__global__ __launch_bounds__(256) void weights_kernel(
    const unsigned short* __restrict__ Qh, const unsigned short* __restrict__ Kh,
    const float* __restrict__ Z, float* __restrict__ wgtbuf,
    float* __restrict__ wout)
{
    const int t = threadIdx.x;
    const int w = t >> 6;
    const int l = t & 63;
    const int idx = blockIdx.x * 4 + w;       // idx = b*L + q
    const int b = idx >> 11;
    const int q = idx & 2047;
    const int h = l >> 3;
    const int jslot = l & 7;

    bf16x8 qv[8];
    {
        const bf16x8* qp = (const bf16x8*)&Qh[(((size_t)b * HH + h) * LL + q) * DKK];
#pragma unroll
        for (int i = 0; i < 8; ++i) qv[i] = qp[i];
    }
    const float zinv = 1.0f / Z[((size_t)b * HH + h) * LL + q];

    float e[4];
#pragma unroll
    for (int c = 0; c < 4; ++c) {
        const int j = jslot + 8 * c;
        const int k = q - WBAND + j;
        float a = 0.f;
        if (j < NBAND && k >= 0 && k < LL) {
            const bf16x8* kp = (const bf16x8*)&Kh[(((size_t)b * HH + h) * LL + k) * DKK];
            float s = 0.f;
#pragma unroll
            for (int i = 0; i < 8; ++i) {
                const bf16x8 ka = kp[i];
#pragma unroll
                for (int ee = 0; ee < 8; ++ee)
                    s += bf2f((unsigned short)qv[i][ee]) * bf2f((unsigned short)ka[ee]);
            }
            a = __expf(s) * zinv;
        }
        e[c] = a;
    }

#pragma unroll
    for (int m = 8; m <= 32; m <<= 1)
#pragma unroll
        for (int c = 0; c < 4; ++c)
            e[c] += __shfl_xor(e[c], m, 64);

    float att[4];
    float part = 0.f;
#pragma unroll
    for (int c = 0; c < 4; ++c) {
        const int j = jslot + 8 * c;
        const float dd = (float)(j - WBAND);
        att[c] = (j < NBAND) ? e[c] * __expf(-0.5f * dd * dd) : 0.f;
        part += att[c];
    }
#pragma unroll
    for (int m = 1; m <= 4; m <<= 1)
        part += __shfl_xor(part, m, 64);
    const float winv = 1.0f / part;

    if (h == 0) {
        float* wrow = &wout[((size_t)b * LL + q) * LL];
#pragma unroll
        for (int c = 0; c < 4; ++c) {
            const int j = jslot + 8 * c;
            if (j < NBAND) {
                const float wv = att[c] * winv;
                wgtbuf[(size_t)idx * 32 + j] = wv;
                const int k = q - WBAND + j;
                if (k >= 0 && k < LL) wrow[k] = wv;
            }
        }
    }
}

// ---------------------------------------------------------------------------
// out: grid (L/8, B). Per block: 8 q rows. Register sliding window over v.
// ---------------------------------------------------------------------------
__global__ __launch_bounds__(256) void out_kernel(
    const float* __restrict__ wgtbuf, const float* __restrict__ v,
    float* __restrict__ out)
{
    __shared__ float lw[8][NBAND];
    const int t  = threadIdx.x;
    const int q0 = blockIdx.x * 8;
    const int b  = blockIdx.y;

    if (t < 8 * NBAND) {
        const int qq = t / NBAND;
        const int j  = t - qq * NBAND;
        lw[qq][j] = wgtbuf[((size_t)b * LL + q0 + qq) * 32 + j];
    }
    __syncthreads();

    const int qsub = t >> 7;
    const int d4   = t & 127;
    const int qs   = q0 + qsub * 4;
    const int kbase = qs - WBAND;
    f32x4 acc[4] = {{0,0,0,0},{0,0,0,0},{0,0,0,0},{0,0,0,0}};
#pragma unroll
    for (int kk = 0; kk < 28; ++kk) {
        const int k = kbase + kk;
        f32x4 vv = {0.f, 0.f, 0.f, 0.f};
        if (k >= 0 && k < LL)
            vv = *(const f32x4*)&v[((size_t)k * BB + b) * DD + d4 * 4];
#pragma unroll
        for (int qi = 0; qi < 4; ++qi) {
            const int j = kk - qi;
            if (j >= 0 && j < NBAND) {
                const float wv = lw[qsub * 4 + qi][j];
                acc[qi][0] += wv * vv[0]; acc[qi][1] += wv * vv[1];
                acc[qi][2] += wv * vv[2]; acc[qi][3] += wv * vv[3];
            }
        }
    }
#pragma unroll
    for (int qi = 0; qi < 4; ++qi) {
        const int q = qs + qi;
        __builtin_nontemporal_store(acc[qi],
            (f32x4*)&out[((size_t)q * BB + b) * DD + d4 * 4]);
    }
}

// ---------------------------------------------------------------------------
extern "C" void kernel_launch(void* const* d_in, const int* in_sizes, int n_in,
                              void* d_out, int out_size, void* d_ws, size_t ws_size,
                              hipStream_t stream) {
    const float* q  = (const float*)d_in[0];
    const float* k  = (const float*)d_in[1];
    const float* v  = (const float*)d_in[2];
    const float* Wq = (const float*)d_in[3];
    const float* bq = (const float*)d_in[4];
    const float* Wk = (const float*)d_in[5];
    const float* bk = (const float*)d_in[6];

    float* out  = (float*)d_out;                       // [L,B,D]
    float* wout = out + (size_t)LL * BB * DD;          // [B,L,L]

    unsigned short* Qh = (unsigned short*)d_ws;                 // bf16 [B,H,L,DK] 8 MB
    unsigned short* Kh = Qh + (size_t)BB * HH * LL * DKK;       // bf16 8 MB
    float* Z      = (float*)(Kh + (size_t)BB * HH * LL * DKK);  // [B*H*L] 256 KB
    float* wgtbuf = Z + (size_t)BB * HH * LL;                   // [B*L][32] 1 MB

    proj_mfma<<<dim3(LL * BB / 128, DD / 128, 2), 256, 0, stream>>>(
        q, k, Wq, Wk, bq, bk, Qh, Kh, wout);

    scorez_mfma<<<dim3(LL / 64, BB * HH), 256, 0, stream>>>(Qh, Kh, Z, wout);

    weights_kernel<<<BB * LL / 4, 256, 0, stream>>>(Qh, Kh, Z, wgtbuf, wout);

    out_kernel<<<dim3(LL / 8, BB), 256, 0, stream>>>(wgtbuf, v, out);
}